// Round 7
// baseline (77.253 us; speedup 1.0000x reference)
//
#include <hip/hip_runtime.h>
#include <hip/hip_bf16.h>
#include <limits.h>

// Problem constants (from reference)
#define BB   4
#define NN   2048
#define CC   512
#define TSZ  9
#define TSTEP 6
#define TCUT 2
#define GRIDW 120
#define CMS  132                          // padded cellmap stride (rows & cols)
#define CMSZ (CMS * CMS)                  // per-batch padded cells
#define TILE_ELEMS (CC * TSZ * TSZ)       // 41472
#define OUT_PER_TILE (TILE_ELEMS + 1)     // 41473 (f_ns entry + tile)

// ---------------- Kernel 1: fused init + scatter + bbox + select ----------------
// Single block, 1024 threads. All stages ordered by __syncthreads().
// nT per batch <= 21*21 = 441 < 1024 -> single selection pass per batch.
// Produces: f_ns (K floats) and tileinfo[k] = (b<<16)|(gy0<<8)|gx0.
__global__ __launch_bounds__(1024) void setup_kernel(
        const int* __restrict__ ys, const int* __restrict__ xs,
        int* __restrict__ cellmap, int* __restrict__ tileinfo,
        float* __restrict__ f_ns) {
    __shared__ int s_off;
    __shared__ int s_wave[16];
    __shared__ int s_red[16][4];
    __shared__ int s_bbox[4];
    const int tid = threadIdx.x;
    const int lane = tid & 63;
    const int wid = tid >> 6;
    if (tid == 0) s_off = 0;

    // --- init padded cellmap to -1 (int4 stores) ---
    int4* __restrict__ cm4 = (int4*)cellmap;
    for (int i = tid; i < BB * CMSZ / 4; i += 1024)
        cm4[i] = make_int4(-1, -1, -1, -1);
    __syncthreads();

    // --- scatter points ---
    for (int i = tid; i < BB * NN; i += 1024) {
        int y = ys[i], x = xs[i];
        if (y > -1) {                      // reference filters ys > -1
            int b = i >> 11;
            cellmap[b * CMSZ + y * CMS + x] = i - (b << 11);
        }
    }
    __syncthreads();

    // --- per batch: bbox reduce, then select + ordered compaction ---
    for (int b = 0; b < BB; ++b) {
        int ymin = INT_MAX, ymax = INT_MIN, xmin = INT_MAX, xmax = INT_MIN;
        for (int j = tid; j < NN; j += 1024) {
            int y = ys[b * NN + j], x = xs[b * NN + j];
            if (y > -1) {
                ymin = min(ymin, y); ymax = max(ymax, y);
                xmin = min(xmin, x); xmax = max(xmax, x);
            }
        }
        #pragma unroll
        for (int off = 32; off; off >>= 1) {
            ymin = min(ymin, __shfl_xor(ymin, off));
            ymax = max(ymax, __shfl_xor(ymax, off));
            xmin = min(xmin, __shfl_xor(xmin, off));
            xmax = max(xmax, __shfl_xor(xmax, off));
        }
        if (lane == 0) {
            s_red[wid][0] = ymin; s_red[wid][1] = ymax;
            s_red[wid][2] = xmin; s_red[wid][3] = xmax;
        }
        __syncthreads();
        if (tid == 0) {
            int a = INT_MAX, bx = INT_MIN, c = INT_MAX, d = INT_MIN;
            for (int w = 0; w < 16; ++w) {
                a = min(a, s_red[w][0]); bx = max(bx, s_red[w][1]);
                c = min(c, s_red[w][2]); d = max(d, s_red[w][3]);
            }
            s_bbox[0] = a; s_bbox[1] = bx; s_bbox[2] = c; s_bbox[3] = d;
        }
        __syncthreads();
        ymin = s_bbox[0]; ymax = s_bbox[1]; xmin = s_bbox[2]; xmax = s_bbox[3];

        int nH = (ymax - ymin + 1) / TSTEP + 1;   // (H - T_SZ)//T_STEP + 1
        int nW = (xmax - xmin + 1) / TSTEP + 1;
        int nT = nH * nW;                          // <= 441 < 1024: single pass

        bool m = false;
        int gy0 = 0, gx0 = 0;
        if (tid < nT) {
            int ti = tid / nW, tj = tid - ti * nW;
            gy0 = ymin + ti * TSTEP;
            gx0 = xmin + tj * TSTEP;
            // center 5x5: 25 independent loads (padded map -> no bounds checks)
            const int* __restrict__ bp =
                cellmap + b * CMSZ + (gy0 + TCUT) * CMS + (gx0 + TCUT);
            int acc = -1;
            #pragma unroll
            for (int dy = 0; dy < 5; ++dy)
                #pragma unroll
                for (int dx = 0; dx < 5; ++dx)
                    acc = max(acc, bp[dy * CMS + dx]);
            m = (acc >= 0);
        }
        unsigned long long bal = __ballot(m);
        int lpre = __popcll(bal & ((1ull << lane) - 1ull));
        if (lane == 0) s_wave[wid] = (int)__popcll(bal);
        __syncthreads();
        if (tid == 0) {
            int acc = s_off;
            for (int w = 0; w < 16; ++w) { int v = s_wave[w]; s_wave[w] = acc; acc += v; }
            s_off = acc;
        }
        __syncthreads();
        if (m) {
            int idx = s_wave[wid] + lpre;
            tileinfo[idx] = (b << 16) | (gy0 << 8) | gx0;
            f_ns[idx] = (float)b;
        }
        __syncthreads();
    }
}

// ---------------- Kernel 2: fill output tiles, one block per (tile, 64-ch chunk) ----------------
// grid = K*8. Pre-zeroed LDS buffer; float4 gather of occupied point slices ->
// LDS (layout == output order), then flat conflict-free float4 LDS->global copy.
__global__ __launch_bounds__(256) void fill_kernel(
        const float* __restrict__ feats, const int* __restrict__ cellmap,
        const int* __restrict__ tileinfo, float* __restrict__ out_tiles) {
    __shared__ int s_list[81];            // compact occupied list: (n<<7)|ce
    __shared__ int s_wcnt[2];
    __shared__ int s_cnt;
    __shared__ __align__(16) float s_f[64 * 81];   // flat == output order, 20.7 KB

    const int tid = threadIdx.x;
    const int lane = tid & 63;
    const int wid = tid >> 6;
    const int k  = blockIdx.x >> 3;
    const int cb = (blockIdx.x & 7) << 6;          // channel base of this chunk

    const int info = tileinfo[k];
    const int b = info >> 16;
    const int gy0 = (info >> 8) & 255;
    const int gx0 = info & 255;

    // zero the chunk buffer; unoccupied cells stay 0
    const float4 z = make_float4(0.f, 0.f, 0.f, 0.f);
    for (int f4 = tid; f4 < 1296; f4 += 256) ((float4*)s_f)[f4] = z;

    int n = -1;
    if (tid < 81) {
        int r = tid / 9, c = tid - r * 9;
        n = cellmap[b * CMSZ + (gy0 + r) * CMS + (gx0 + c)];
    }
    bool occ = (tid < 81) && (n >= 0);
    unsigned long long bal = __ballot(occ);
    int pre = __popcll(bal & ((1ull << lane) - 1ull));
    if (lane == 0 && wid < 2) s_wcnt[wid] = (int)__popcll(bal);
    __syncthreads();
    if (occ) {
        int idx = (wid == 1 ? s_wcnt[0] : 0) + pre;
        s_list[idx] = (n << 7) | tid;     // n<=2047 (11b) | cell (7b)
    }
    if (tid == 0) s_cnt = s_wcnt[0] + s_wcnt[1];
    __syncthreads();

    const int nk = s_cnt;
    const float* __restrict__ fb = feats + (size_t)b * (NN * CC) + cb;

    // gather: occupied points' 64-channel slice, float4 per thread (coalesced 256B/point)
    for (int e = tid; e < nk * 16; e += 256) {
        int slot = e >> 4, q = e & 15;
        int pk = s_list[slot];
        int pn = pk >> 7, ce = pk & 127;
        float4 v = *(const float4*)(fb + pn * CC + q * 4);
        s_f[(q * 4 + 0) * 81 + ce] = v.x;
        s_f[(q * 4 + 1) * 81 + ce] = v.y;
        s_f[(q * 4 + 2) * 81 + ce] = v.z;
        s_f[(q * 4 + 3) * 81 + ce] = v.w;
    }
    __syncthreads();

    // flat copy: 1296 float4, conflict-free ds_read_b128, coalesced stores
    float* __restrict__ outc = out_tiles + (size_t)k * TILE_ELEMS + (size_t)cb * 81;
    for (int f4 = tid; f4 < 1296; f4 += 256) {
        float4 v = ((const float4*)s_f)[f4];
        *(float4*)(outc + f4 * 4) = v;
    }
}

extern "C" void kernel_launch(void* const* d_in, const int* in_sizes, int n_in,
                              void* d_out, int out_size, void* d_ws, size_t ws_size,
                              hipStream_t stream) {
    const float* feats = (const float*)d_in[0];
    const int* ys = (const int*)d_in[1];
    const int* xs = (const int*)d_in[2];
    float* out = (float*)d_out;

    char* ws = (char*)d_ws;
    int* cellmap = (int*)ws;                              // 4*132*132*4 = 278784 B
    int* tileinfo = (int*)(ws + BB * CMSZ * 4 + 256);     // K ints (<= ~7 KB)

    const int K = out_size / OUT_PER_TILE;                // number of selected tiles
    float* f_ns = out;                                    // first K floats
    float* out_tiles = out + K;                           // K * 41472 floats

    setup_kernel<<<1, 1024, 0, stream>>>(ys, xs, cellmap, tileinfo, f_ns);
    fill_kernel<<<K * 8, 256, 0, stream>>>(feats, cellmap, tileinfo, out_tiles);
}